// Round 1
// 1428.848 us; speedup vs baseline: 1.2998x; 1.2998x over previous
//
#include <hip/hip_runtime.h>
#include <math.h>

typedef __bf16 bf16;
typedef bf16  v8bf __attribute__((ext_vector_type(8)));
typedef bf16  v2bf __attribute__((ext_vector_type(2)));
typedef float v4f  __attribute__((ext_vector_type(4)));

#define LB __launch_bounds__(256)

static inline int cdiv(int a, int b){ return (a + b - 1) / b; }

// ---------------- CSR build ----------------

__global__ LB void zero_int(int* __restrict__ p, int n){
  int i = blockIdx.x * 256 + threadIdx.x;
  if (i < n) p[i] = 0;
}

__global__ LB void count_edges(const int* __restrict__ ei, const int* __restrict__ et,
                               int* __restrict__ cnt, int E, int R){
  int e = blockIdx.x * 256 + threadIdx.x;
  if (e >= E) return;
  int dst = ei[E + e];
  int ty  = et[e];
  atomicAdd(&cnt[dst * R + ty], 1);
}

__global__ LB void block_sum_k(const int* __restrict__ cnt, int* __restrict__ bsum, int NS){
  __shared__ int sh[256];
  int t = threadIdx.x;
  int base = blockIdx.x * 1024;
  int s = 0;
  for (int i = t; i < 1024; i += 256){ int g = base + i; if (g < NS) s += cnt[g]; }
  sh[t] = s; __syncthreads();
  for (int d = 128; d > 0; d >>= 1){ if (t < d) sh[t] += sh[t + d]; __syncthreads(); }
  if (t == 0) bsum[blockIdx.x] = sh[0];
}

// single block, nb <= 256 (NS <= 262144)
__global__ LB void scan_bsum_k(int* __restrict__ bsum, int nb){
  __shared__ int sh[256];
  int t = threadIdx.x;
  int v = (t < nb) ? bsum[t] : 0;
  sh[t] = v; __syncthreads();
  for (int d = 1; d < 256; d <<= 1){
    int add = (t >= d) ? sh[t - d] : 0;
    __syncthreads();
    sh[t] += add;
    __syncthreads();
  }
  if (t < nb) bsum[t] = sh[t] - v;  // exclusive
}

__global__ LB void scan_scatter_k(const int* __restrict__ cnt, const int* __restrict__ bsum,
                                  int* __restrict__ off, int* __restrict__ cursor,
                                  float* __restrict__ degInv, int NS){
  __shared__ int sh[256];
  int t = threadIdx.x;
  int base = blockIdx.x * 1024 + t * 4;
  int v[4];
  #pragma unroll
  for (int j = 0; j < 4; ++j){ int g = base + j; v[j] = (g < NS) ? cnt[g] : 0; }
  int tsum = v[0] + v[1] + v[2] + v[3];
  sh[t] = tsum; __syncthreads();
  for (int d = 1; d < 256; d <<= 1){
    int add = (t >= d) ? sh[t - d] : 0;
    __syncthreads();
    sh[t] += add;
    __syncthreads();
  }
  int o = bsum[blockIdx.x] + sh[t] - tsum;
  #pragma unroll
  for (int j = 0; j < 4; ++j){
    int g = base + j;
    if (g < NS){
      off[g] = o;
      cursor[g] = o;
      degInv[g] = 1.0f / (float)(v[j] > 0 ? v[j] : 1);
      o += v[j];
      if (g == NS - 1) off[NS] = o;
    }
  }
}

__global__ LB void fill_edges(const int* __restrict__ ei, const int* __restrict__ et,
                              int* __restrict__ cursor, int* __restrict__ srcS, int E, int R){
  int e = blockIdx.x * 256 + threadIdx.x;
  if (e >= E) return;
  int src = ei[e];
  int dst = ei[E + e];
  int ty  = et[e];
  int pos = atomicAdd(&cursor[dst * R + ty], 1);
  srcS[pos] = src;
}

// ---------------- mean aggregation (bf16 X, D=128: v2bf per lane over a wave64) ----------------
// X rows are 256B; one wave per segment; 4 row-gathers in flight (unroll 4).

__global__ LB void agg_mean_k(const bf16* __restrict__ X, const int* __restrict__ srcS,
                              const int* __restrict__ off, const float* __restrict__ degInv,
                              bf16* __restrict__ mean, int NS){
  int w = (int)(((size_t)blockIdx.x * blockDim.x + threadIdx.x) >> 6);  // one wave per segment
  int lane = threadIdx.x & 63;
  if (w >= NS) return;
  int s0 = off[w], s1 = off[w + 1];
  float ax = 0.f, ay = 0.f;
  int i = s0;
  for (; i + 4 <= s1; i += 4){
    int j0 = srcS[i], j1 = srcS[i + 1], j2 = srcS[i + 2], j3 = srcS[i + 3];
    v2bf u0 = *(const v2bf*)(X + (size_t)j0 * 128 + lane * 2);
    v2bf u1 = *(const v2bf*)(X + (size_t)j1 * 128 + lane * 2);
    v2bf u2 = *(const v2bf*)(X + (size_t)j2 * 128 + lane * 2);
    v2bf u3 = *(const v2bf*)(X + (size_t)j3 * 128 + lane * 2);
    ax += (float)u0[0] + (float)u1[0] + (float)u2[0] + (float)u3[0];
    ay += (float)u0[1] + (float)u1[1] + (float)u2[1] + (float)u3[1];
  }
  for (; i < s1; ++i){
    int j = srcS[i];
    v2bf u = *(const v2bf*)(X + (size_t)j * 128 + lane * 2);
    ax += (float)u[0]; ay += (float)u[1];
  }
  float di = degInv[w];
  v2bf o; o[0] = (bf16)(ax * di); o[1] = (bf16)(ay * di);
  *(v2bf*)(mean + (size_t)w * 128 + lane * 2) = o;
}

// ---------------- weight prep: fp32 [K][N] -> bf16 BT [N][KP] (zero-pad K->KP) ----------------

__global__ LB void prep_bt(const float* __restrict__ W, bf16* __restrict__ BT,
                           int K, int Nc, int KP){
  int idx = blockIdx.x * 256 + threadIdx.x;
  if (idx >= Nc * KP) return;
  int n = idx / KP, k = idx - n * KP;
  BT[idx] = (k < K) ? (bf16)W[(size_t)k * Nc + n] : (bf16)0.f;
}

// stacked [W_root ; W_rel_flat] -> BT [D][3D]
__global__ LB void prep_stack(const float* __restrict__ Wroot, const float* __restrict__ Wrel,
                              bf16* __restrict__ BT, int D){
  int KP = 3 * D;
  int idx = blockIdx.x * 256 + threadIdx.x;
  if (idx >= D * KP) return;
  int n = idx / KP, k = idx - n * KP;
  float v = (k < D) ? Wroot[(size_t)k * D + n] : Wrel[(size_t)(k - D) * D + n];
  BT[idx] = (bf16)v;
}

// ---------------- bf16 MFMA GEMM: C = op( [A|A2] @ B + bias ) ----------------
// A fp32 row-major (cast at staging) when !ABF, bf16 row-major when ABF.
// B pre-transposed bf16 BT[n][KP].
// DUALA: k < KA from A (lda), k >= KA from A2 (lda2). KA % 32 == 0 required.
// CBF: write C as bf16 (else fp32).

template<int BN, bool LRELU, bool DUALA, bool ABF, bool CBF>
__global__ LB void gemm_mfma(const void* __restrict__ Av, int lda,
                             const void* __restrict__ A2v, int lda2, int KA,
                             const bf16* __restrict__ BT, int KP,
                             void* __restrict__ Cv, int ldc,
                             const float* __restrict__ bias,
                             int M, int K){
  __shared__ __align__(16) bf16 As[64][40];   // pad 8 bf16 -> 2-way conflicts only (free)
  __shared__ __align__(16) bf16 Bs[BN][40];
  const int t = threadIdx.x;
  const int row0 = blockIdx.x * 64;
  const int col0 = blockIdx.y * BN;
  const int wv = t >> 6, ln = t & 63;
  const int mr = ln & 15, quad = ln >> 4;
  const int sr = t >> 2;          // staging row 0..63
  const int sc = (t & 3) * 8;     // staging col 0,8,16,24

  v4f acc[BN / 16];
  #pragma unroll
  for (int f = 0; f < BN / 16; ++f) acc[f] = (v4f)0.f;

  for (int k0 = 0; k0 < KP; k0 += 32){
    // ---- stage A ----
    {
      int gr = row0 + sr;
      int gk = k0 + sc;
      bool useA2 = DUALA && (k0 >= KA);
      if (ABF){
        const bf16* src;
        if (useA2) src = (const bf16*)A2v + (size_t)gr * lda2 + (gk - KA);
        else       src = (const bf16*)Av  + (size_t)gr * lda  + gk;
        v8bf val;
        if (gr < M && gk + 8 <= K){
          val = *(const v8bf*)src;
        } else {
          #pragma unroll
          for (int j = 0; j < 8; ++j)
            val[j] = (gr < M && gk + j < K) ? src[j] : (bf16)0.f;
        }
        *(v8bf*)&As[sr][sc] = val;
      } else {
        const float* src;
        if (useA2) src = (const float*)A2v + (size_t)gr * lda2 + (gk - KA);
        else       src = (const float*)Av  + (size_t)gr * lda  + gk;
        bf16 tmp[8];
        if (gr < M && gk + 8 <= K){
          float4 f0 = *(const float4*)src;
          float4 f1 = *(const float4*)(src + 4);
          tmp[0]=(bf16)f0.x; tmp[1]=(bf16)f0.y; tmp[2]=(bf16)f0.z; tmp[3]=(bf16)f0.w;
          tmp[4]=(bf16)f1.x; tmp[5]=(bf16)f1.y; tmp[6]=(bf16)f1.z; tmp[7]=(bf16)f1.w;
        } else {
          #pragma unroll
          for (int j = 0; j < 8; ++j)
            tmp[j] = (gr < M && gk + j < K) ? (bf16)src[j] : (bf16)0.f;
        }
        *(v8bf*)&As[sr][sc] = *(v8bf*)tmp;
      }
    }
    // ---- stage B (already bf16, transposed) ----
    if (BN == 64 || t < 128){
      *(v8bf*)&Bs[sr][sc] = *(const v8bf*)&BT[(size_t)(col0 + sr) * KP + k0 + sc];
    }
    __syncthreads();
    // ---- MFMA ----
    v8bf a = *(v8bf*)&As[wv * 16 + mr][quad * 8];
    #pragma unroll
    for (int f = 0; f < BN / 16; ++f){
      v8bf b = *(v8bf*)&Bs[f * 16 + mr][quad * 8];
      acc[f] = __builtin_amdgcn_mfma_f32_16x16x32_bf16(a, b, acc[f], 0, 0, 0);
    }
    __syncthreads();
  }

  // ---- epilogue: D[row=quad*4+r][col=mr] per 16x16 frag ----
  #pragma unroll
  for (int f = 0; f < BN / 16; ++f){
    int gc = col0 + f * 16 + mr;
    float bv = bias[gc];
    #pragma unroll
    for (int r = 0; r < 4; ++r){
      int gr = row0 + wv * 16 + quad * 4 + r;
      if (gr < M){
        float v = acc[f][r] + bv;
        if (LRELU) v = (v >= 0.f) ? v : 0.01f * v;
        if (CBF) ((bf16*)Cv)[(size_t)gr * ldc + gc] = (bf16)v;
        else     ((float*)Cv)[(size_t)gr * ldc + gc] = v;
      }
    }
  }
}

// ---------------- head: softmax(H @ W_o2 + b_o2), D=128, 2 classes, H bf16 ----------------

__global__ LB void head_softmax(const bf16* __restrict__ H, const float* __restrict__ Wo2,
                                const float* __restrict__ bo2, float* __restrict__ out, int Nn){
  int gtid = blockIdx.x * 256 + threadIdx.x;
  int node = gtid >> 5;          // 32 lanes per node
  int lane = gtid & 31;
  if (node >= Nn) return;
  float l0 = 0.f, l1 = 0.f;
  #pragma unroll
  for (int kk = 0; kk < 4; ++kk){
    int k = lane + kk * 32;
    float h = (float)H[(size_t)node * 128 + k];
    l0 = fmaf(h, Wo2[k * 2 + 0], l0);
    l1 = fmaf(h, Wo2[k * 2 + 1], l1);
  }
  #pragma unroll
  for (int m = 16; m >= 1; m >>= 1){
    l0 += __shfl_xor(l0, m, 64);
    l1 += __shfl_xor(l1, m, 64);
  }
  if (lane == 0){
    l0 += bo2[0]; l1 += bo2[1];
    float mx = fmaxf(l0, l1);
    float e0 = __expf(l0 - mx), e1 = __expf(l1 - mx);
    float inv = 1.f / (e0 + e1);
    out[(size_t)node * 2 + 0] = e0 * inv;
    out[(size_t)node * 2 + 1] = e1 * inv;
  }
}

// ---------------- launch ----------------

extern "C" void kernel_launch(void* const* d_in, const int* in_sizes, int n_in,
                              void* d_out, int out_size, void* d_ws, size_t ws_size,
                              hipStream_t stream) {
  const float* des    = (const float*)d_in[0];
  const float* tweet  = (const float*)d_in[1];
  const float* prop   = (const float*)d_in[2];
  const int*   ei     = (const int*)d_in[3];
  const int*   et     = (const int*)d_in[4];
  const float* W_des  = (const float*)d_in[5];
  const float* b_des  = (const float*)d_in[6];
  const float* W_tw   = (const float*)d_in[7];
  const float* b_tw   = (const float*)d_in[8];
  const float* W_pr   = (const float*)d_in[9];
  const float* b_pr   = (const float*)d_in[10];
  const float* W_in   = (const float*)d_in[11];
  const float* b_in   = (const float*)d_in[12];
  const float* W_rel  = (const float*)d_in[13];
  const float* W_root = (const float*)d_in[14];
  const float* b_rg   = (const float*)d_in[15];
  const float* W_o1   = (const float*)d_in[16];
  const float* b_o1   = (const float*)d_in[17];
  const float* W_o2   = (const float*)d_in[18];
  const float* b_o2   = (const float*)d_in[19];

  const int Nn = in_sizes[0] / 768;         // 100000
  const int E  = in_sizes[4];               // 3200000
  const int q  = in_sizes[6];               // 32
  const int D  = in_sizes[12];              // 128
  const int R  = in_sizes[13] / (D * D);    // 2
  const int NS = Nn * R;
  const int K3 = 3 * q;                     // 96

  // workspace carve (256B aligned)
  char* p = (char*)d_ws;
  auto carve = [&](size_t bytes) -> void* {
    void* r = (void*)p;
    p += (bytes + 255) & ~(size_t)255;
    return r;
  };
  int*   cnt     = (int*)  carve((size_t)NS * 4);
  int*   off     = (int*)  carve((size_t)(NS + 1) * 4);
  int*   cursor  = (int*)  carve((size_t)NS * 4);
  float* degInv  = (float*)carve((size_t)NS * 4);
  int*   bsum    = (int*)  carve(4096 * 4);
  int*   srcS    = (int*)  carve((size_t)E * 4);
  bf16*  bufA    = (bf16*) carve((size_t)Nn * D * 2);
  bf16*  bufB    = (bf16*) carve((size_t)Nn * D * 2);
  bf16*  mean    = (bf16*) carve((size_t)Nn * R * D * 2);
  bf16*  dtp     = mean;                    // N x 96 bf16 overlays mean (dead before agg)
  bf16*  BT_des  = (bf16*) carve((size_t)q * 768 * 2);
  bf16*  BT_tw   = (bf16*) carve((size_t)q * 768 * 2);
  bf16*  BT_pr   = (bf16*) carve((size_t)q * 32 * 2);
  bf16*  BT_in   = (bf16*) carve((size_t)D * K3 * 2);
  bf16*  BT_st   = (bf16*) carve((size_t)D * 3 * D * 2);
  bf16*  BT_o1   = (bf16*) carve((size_t)D * D * 2);

  const int NB1 = cdiv(NS, 1024);

  // ---- CSR build (once; shared by both RGCN layers) ----
  zero_int<<<cdiv(NS, 256), 256, 0, stream>>>(cnt, NS);
  count_edges<<<cdiv(E, 256), 256, 0, stream>>>(ei, et, cnt, E, R);
  block_sum_k<<<NB1, 256, 0, stream>>>(cnt, bsum, NS);
  scan_bsum_k<<<1, 256, 0, stream>>>(bsum, NB1);
  scan_scatter_k<<<NB1, 256, 0, stream>>>(cnt, bsum, off, cursor, degInv, NS);
  fill_edges<<<cdiv(E, 256), 256, 0, stream>>>(ei, et, cursor, srcS, E, R);

  // ---- weight prep (bf16, transposed, K zero-padded to mult of 32) ----
  prep_bt<<<cdiv(q * 768, 256), 256, 0, stream>>>(W_des, BT_des, 768, q, 768);
  prep_bt<<<cdiv(q * 768, 256), 256, 0, stream>>>(W_tw,  BT_tw,  768, q, 768);
  prep_bt<<<cdiv(q * 32, 256), 256, 0, stream>>>(W_pr,  BT_pr,  14,  q, 32);
  prep_bt<<<cdiv(D * K3, 256), 256, 0, stream>>>(W_in,  BT_in,  K3,  D, K3);
  prep_stack<<<cdiv(D * 3 * D, 256), 256, 0, stream>>>(W_root, W_rel, BT_st, D);
  prep_bt<<<cdiv(D * D, 256), 256, 0, stream>>>(W_o1,  BT_o1,  D,   D, D);

  const int gx = cdiv(Nn, 64);

  // ---- encoders -> dtp[:, 0:32 | 32:64 | 64:96] (fp32 A, bf16 C) ----
  gemm_mfma<32, true, false, false, true><<<dim3(gx, 1), 256, 0, stream>>>(
      des, 768, nullptr, 0, 0, BT_des, 768, dtp + 0, K3, b_des, Nn, 768);
  gemm_mfma<32, true, false, false, true><<<dim3(gx, 1), 256, 0, stream>>>(
      tweet, 768, nullptr, 0, 0, BT_tw, 768, dtp + q, K3, b_tw, Nn, 768);
  gemm_mfma<32, true, false, false, true><<<dim3(gx, 1), 256, 0, stream>>>(
      prop, 14, nullptr, 0, 0, BT_pr, 32, dtp + 2 * q, K3, b_pr, Nn, 14);

  // ---- x = lrelu(dtp @ W_in + b_in) -> bufA (bf16 A, bf16 C) ----
  gemm_mfma<64, true, false, true, true><<<dim3(gx, 2), 256, 0, stream>>>(
      dtp, K3, nullptr, 0, 0, BT_in, K3, bufA, D, b_in, Nn, K3);

  const int aggGrid = cdiv(NS * 64, 256);

  // ---- RGCN layer 1: bufA -> bufB (fused root+rel, K=384) ----
  agg_mean_k<<<aggGrid, 256, 0, stream>>>(bufA, srcS, off, degInv, mean, NS);
  gemm_mfma<64, false, true, true, true><<<dim3(gx, 2), 256, 0, stream>>>(
      bufA, D, mean, R * D, D, BT_st, 3 * D, bufB, D, b_rg, Nn, 3 * D);

  // ---- RGCN layer 2: bufB -> bufA ----
  agg_mean_k<<<aggGrid, 256, 0, stream>>>(bufB, srcS, off, degInv, mean, NS);
  gemm_mfma<64, false, true, true, true><<<dim3(gx, 2), 256, 0, stream>>>(
      bufB, D, mean, R * D, D, BT_st, 3 * D, bufA, D, b_rg, Nn, 3 * D);

  // ---- head ----
  gemm_mfma<64, true, false, true, true><<<dim3(gx, 2), 256, 0, stream>>>(
      bufA, D, nullptr, 0, 0, BT_o1, D, bufB, D, b_o1, Nn, D);
  head_softmax<<<cdiv(Nn * 32, 256), 256, 0, stream>>>(bufB, W_o2, b_o2, (float*)d_out, Nn);
}

// Round 2
// 1189.721 us; speedup vs baseline: 1.5610x; 1.2010x over previous
//
#include <hip/hip_runtime.h>
#include <math.h>

typedef __bf16 bf16;
typedef bf16  v8bf __attribute__((ext_vector_type(8)));
typedef bf16  v2bf __attribute__((ext_vector_type(2)));
typedef float v4f  __attribute__((ext_vector_type(4)));

#define LB __launch_bounds__(256)

static inline int cdiv(int a, int b){ return (a + b - 1) / b; }

// ---------------- bucketed CSR build ----------------
// Buckets of 512 nodes (dst >> 9). NB = cdiv(N,512) <= 256. R == 2 assumed for
// seg->bucket recovery shift; bucket computed as (seg / R) >> 9 with runtime R.

#define PNB   256     // max buckets
#define CHUNK 4096    // edges per partition block
#define SPB   1024    // segments per bucket (512 * R, R=2)

__global__ LB void zero_int(int* __restrict__ p, int n){
  int i = blockIdx.x * 256 + threadIdx.x;
  if (i < n) p[i] = 0;
}

// LDS histogram of dst>>9, one global atomic per (block,bucket)
__global__ LB void bucket_count_k(const int* __restrict__ ei, int* __restrict__ gCnt, int E){
  __shared__ int lh[PNB];
  int t = threadIdx.x;
  int base = blockIdx.x * CHUNK;
  for (int i = t; i < PNB; i += 256) lh[i] = 0;
  __syncthreads();
  #pragma unroll
  for (int j = 0; j < 16; ++j){
    int i = base + t + j * 256;
    if (i < E){
      int d = ei[E + i];
      atomicAdd(&lh[d >> 9], 1);
    }
  }
  __syncthreads();
  for (int i = t; i < PNB; i += 256) if (lh[i]) atomicAdd(&gCnt[i], lh[i]);
}

// single block: exclusive scan of NBk bucket counts -> bucketBase, init gCur, off[NS]=E
__global__ LB void bucket_scan_k(const int* __restrict__ gCnt, int* __restrict__ bucketBase,
                                 int* __restrict__ gCur, int* __restrict__ off,
                                 int NBk, int E, int NS){
  __shared__ int sh[256];
  int t = threadIdx.x;
  int v = (t < NBk) ? gCnt[t] : 0;
  sh[t] = v; __syncthreads();
  for (int d = 1; d < 256; d <<= 1){
    int add = (t >= d) ? sh[t - d] : 0;
    __syncthreads();
    sh[t] += add;
    __syncthreads();
  }
  int excl = sh[t] - v;
  if (t < NBk){ bucketBase[t] = excl; gCur[t] = excl; }
  if (t == 0){ bucketBase[NBk] = E; off[NS] = E; }
}

// rank CHUNK edges into LDS by bucket, reserve per-bucket global space (1 atomic
// per bucket per block), stream out coalesced runs into bucket-contiguous regions
__global__ LB void partition_k(const int* __restrict__ ei, const int* __restrict__ et,
                               int* __restrict__ gCur,
                               int* __restrict__ partSrc, int* __restrict__ partSeg,
                               int E, int R){
  __shared__ int lh[PNB];
  __shared__ int lbase[PNB];
  __shared__ int gb[PNB];
  __shared__ int stageSrc[CHUNK];
  __shared__ int stageSeg[CHUNK];
  int t = threadIdx.x;
  int base = blockIdx.x * CHUNK;
  int cntE = E - base; if (cntE > CHUNK) cntE = CHUNK;
  for (int i = t; i < PNB; i += 256) lh[i] = 0;
  __syncthreads();
  int seg_[16], src_[16], pk_[16];
  #pragma unroll
  for (int j = 0; j < 16; ++j){
    int i = t + j * 256;
    if (i < cntE){
      int e = base + i;
      int s  = ei[e];
      int d  = ei[E + e];
      int ty = et[e];
      seg_[j] = d * R + ty;
      src_[j] = s;
      int b = d >> 9;
      int r = atomicAdd(&lh[b], 1);
      pk_[j] = (b << 16) | r;
    } else pk_[j] = -1;
  }
  __syncthreads();
  // exclusive scan of lh -> lbase
  int v = lh[t];
  lbase[t] = v; __syncthreads();
  for (int d = 1; d < 256; d <<= 1){
    int add = (t >= d) ? lbase[t - d] : 0;
    __syncthreads();
    lbase[t] += add;
    __syncthreads();
  }
  int excl = lbase[t] - v;
  int gbase = 0;
  if (v > 0) gbase = atomicAdd(&gCur[t], v);
  __syncthreads();
  lbase[t] = excl;
  gb[t] = gbase;
  __syncthreads();
  // place into staging (bucket-sorted)
  #pragma unroll
  for (int j = 0; j < 16; ++j){
    if (pk_[j] >= 0){
      int b = pk_[j] >> 16, r = pk_[j] & 0xffff;
      int pos = lbase[b] + r;
      stageSrc[pos] = src_[j];
      stageSeg[pos] = seg_[j];
    }
  }
  __syncthreads();
  // stream out: runs of ~16 per bucket, contiguous at gb[b]
  for (int i = t; i < cntE; i += 256){
    int sg = stageSeg[i];
    int b = (sg / R) >> 9;
    int g = gb[b] + (i - lbase[b]);
    partSeg[g] = sg;
    partSrc[g] = stageSrc[i];
  }
}

// one block per bucket: LDS histogram + scan over SPB segments, write off/degInv,
// scatter srcS via LDS cursors into the bucket's contiguous region (single-XCD lines)
__global__ LB void bucket_csr_k(const int* __restrict__ partSrc, const int* __restrict__ partSeg,
                                const int* __restrict__ bucketBase,
                                int* __restrict__ off, float* __restrict__ degInv,
                                int* __restrict__ srcS, int NS, int R){
  __shared__ int lh[SPB];
  __shared__ int lsc[256];
  int b = blockIdx.x, t = threadIdx.x;
  int s0 = bucketBase[b], s1 = bucketBase[b + 1];
  int segBase = b * SPB;
  for (int i = t; i < SPB; i += 256) lh[i] = 0;
  __syncthreads();
  for (int i = s0 + t; i < s1; i += 256)
    atomicAdd(&lh[partSeg[i] - segBase], 1);
  __syncthreads();
  // exclusive scan over SPB (4 per thread)
  int base4 = t * 4;
  int v0 = lh[base4], v1 = lh[base4 + 1], v2 = lh[base4 + 2], v3 = lh[base4 + 3];
  int tsum = v0 + v1 + v2 + v3;
  lsc[t] = tsum; __syncthreads();
  for (int d = 1; d < 256; d <<= 1){
    int add = (t >= d) ? lsc[t - d] : 0;
    __syncthreads();
    lsc[t] += add;
    __syncthreads();
  }
  int o = lsc[t] - tsum;
  int cs[4] = {v0, v1, v2, v3};
  #pragma unroll
  for (int j = 0; j < 4; ++j){
    int ls = base4 + j;
    int g = segBase + ls;
    int c = cs[j];
    if (g < NS){
      off[g] = s0 + o;
      degInv[g] = 1.0f / (float)(c > 0 ? c : 1);
    }
    lh[ls] = o;   // bucket-local cursor start
    o += c;
  }
  __syncthreads();
  for (int i = s0 + t; i < s1; i += 256){
    int sg = partSeg[i];
    int r = atomicAdd(&lh[sg - segBase], 1);
    srcS[s0 + r] = partSrc[i];
  }
}

// ---------------- mean aggregation (bf16 X, D=128: v2bf per lane over a wave64) ----------------

__global__ LB void agg_mean_k(const bf16* __restrict__ X, const int* __restrict__ srcS,
                              const int* __restrict__ off, const float* __restrict__ degInv,
                              bf16* __restrict__ mean, int NS){
  int w = (int)(((size_t)blockIdx.x * blockDim.x + threadIdx.x) >> 6);  // one wave per segment
  int lane = threadIdx.x & 63;
  if (w >= NS) return;
  int s0 = off[w], s1 = off[w + 1];
  float ax = 0.f, ay = 0.f;
  int i = s0;
  for (; i + 4 <= s1; i += 4){
    int j0 = srcS[i], j1 = srcS[i + 1], j2 = srcS[i + 2], j3 = srcS[i + 3];
    v2bf u0 = *(const v2bf*)(X + (size_t)j0 * 128 + lane * 2);
    v2bf u1 = *(const v2bf*)(X + (size_t)j1 * 128 + lane * 2);
    v2bf u2 = *(const v2bf*)(X + (size_t)j2 * 128 + lane * 2);
    v2bf u3 = *(const v2bf*)(X + (size_t)j3 * 128 + lane * 2);
    ax += (float)u0[0] + (float)u1[0] + (float)u2[0] + (float)u3[0];
    ay += (float)u0[1] + (float)u1[1] + (float)u2[1] + (float)u3[1];
  }
  for (; i < s1; ++i){
    int j = srcS[i];
    v2bf u = *(const v2bf*)(X + (size_t)j * 128 + lane * 2);
    ax += (float)u[0]; ay += (float)u[1];
  }
  float di = degInv[w];
  v2bf o; o[0] = (bf16)(ax * di); o[1] = (bf16)(ay * di);
  *(v2bf*)(mean + (size_t)w * 128 + lane * 2) = o;
}

// ---------------- weight prep: fp32 [K][N] -> bf16 BT [N][KP] (zero-pad K->KP) ----------------

__global__ LB void prep_bt(const float* __restrict__ W, bf16* __restrict__ BT,
                           int K, int Nc, int KP){
  int idx = blockIdx.x * 256 + threadIdx.x;
  if (idx >= Nc * KP) return;
  int n = idx / KP, k = idx - n * KP;
  BT[idx] = (k < K) ? (bf16)W[(size_t)k * Nc + n] : (bf16)0.f;
}

// stacked [W_root ; W_rel_flat] -> BT [D][3D]
__global__ LB void prep_stack(const float* __restrict__ Wroot, const float* __restrict__ Wrel,
                              bf16* __restrict__ BT, int D){
  int KP = 3 * D;
  int idx = blockIdx.x * 256 + threadIdx.x;
  if (idx >= D * KP) return;
  int n = idx / KP, k = idx - n * KP;
  float v = (k < D) ? Wroot[(size_t)k * D + n] : Wrel[(size_t)(k - D) * D + n];
  BT[idx] = (bf16)v;
}

// ---------------- bf16 MFMA GEMM: C = op( [A|A2] @ B + bias ) ----------------

template<int BN, bool LRELU, bool DUALA, bool ABF, bool CBF>
__global__ LB void gemm_mfma(const void* __restrict__ Av, int lda,
                             const void* __restrict__ A2v, int lda2, int KA,
                             const bf16* __restrict__ BT, int KP,
                             void* __restrict__ Cv, int ldc,
                             const float* __restrict__ bias,
                             int M, int K){
  __shared__ __align__(16) bf16 As[64][40];   // pad 8 bf16 -> 2-way conflicts only (free)
  __shared__ __align__(16) bf16 Bs[BN][40];
  const int t = threadIdx.x;
  const int row0 = blockIdx.x * 64;
  const int col0 = blockIdx.y * BN;
  const int wv = t >> 6, ln = t & 63;
  const int mr = ln & 15, quad = ln >> 4;
  const int sr = t >> 2;          // staging row 0..63
  const int sc = (t & 3) * 8;     // staging col 0,8,16,24

  v4f acc[BN / 16];
  #pragma unroll
  for (int f = 0; f < BN / 16; ++f) acc[f] = (v4f)0.f;

  for (int k0 = 0; k0 < KP; k0 += 32){
    // ---- stage A ----
    {
      int gr = row0 + sr;
      int gk = k0 + sc;
      bool useA2 = DUALA && (k0 >= KA);
      if (ABF){
        const bf16* src;
        if (useA2) src = (const bf16*)A2v + (size_t)gr * lda2 + (gk - KA);
        else       src = (const bf16*)Av  + (size_t)gr * lda  + gk;
        v8bf val;
        if (gr < M && gk + 8 <= K){
          val = *(const v8bf*)src;
        } else {
          #pragma unroll
          for (int j = 0; j < 8; ++j)
            val[j] = (gr < M && gk + j < K) ? src[j] : (bf16)0.f;
        }
        *(v8bf*)&As[sr][sc] = val;
      } else {
        const float* src;
        if (useA2) src = (const float*)A2v + (size_t)gr * lda2 + (gk - KA);
        else       src = (const float*)Av  + (size_t)gr * lda  + gk;
        bf16 tmp[8];
        if (gr < M && gk + 8 <= K){
          float4 f0 = *(const float4*)src;
          float4 f1 = *(const float4*)(src + 4);
          tmp[0]=(bf16)f0.x; tmp[1]=(bf16)f0.y; tmp[2]=(bf16)f0.z; tmp[3]=(bf16)f0.w;
          tmp[4]=(bf16)f1.x; tmp[5]=(bf16)f1.y; tmp[6]=(bf16)f1.z; tmp[7]=(bf16)f1.w;
        } else {
          #pragma unroll
          for (int j = 0; j < 8; ++j)
            tmp[j] = (gr < M && gk + j < K) ? (bf16)src[j] : (bf16)0.f;
        }
        *(v8bf*)&As[sr][sc] = *(v8bf*)tmp;
      }
    }
    // ---- stage B (already bf16, transposed) ----
    if (BN == 64 || t < 128){
      *(v8bf*)&Bs[sr][sc] = *(const v8bf*)&BT[(size_t)(col0 + sr) * KP + k0 + sc];
    }
    __syncthreads();
    // ---- MFMA ----
    v8bf a = *(v8bf*)&As[wv * 16 + mr][quad * 8];
    #pragma unroll
    for (int f = 0; f < BN / 16; ++f){
      v8bf b = *(v8bf*)&Bs[f * 16 + mr][quad * 8];
      acc[f] = __builtin_amdgcn_mfma_f32_16x16x32_bf16(a, b, acc[f], 0, 0, 0);
    }
    __syncthreads();
  }

  // ---- epilogue: D[row=quad*4+r][col=mr] per 16x16 frag ----
  #pragma unroll
  for (int f = 0; f < BN / 16; ++f){
    int gc = col0 + f * 16 + mr;
    float bv = bias[gc];
    #pragma unroll
    for (int r = 0; r < 4; ++r){
      int gr = row0 + wv * 16 + quad * 4 + r;
      if (gr < M){
        float v = acc[f][r] + bv;
        if (LRELU) v = (v >= 0.f) ? v : 0.01f * v;
        if (CBF) ((bf16*)Cv)[(size_t)gr * ldc + gc] = (bf16)v;
        else     ((float*)Cv)[(size_t)gr * ldc + gc] = v;
      }
    }
  }
}

// ---------------- head: softmax(H @ W_o2 + b_o2), D=128, 2 classes, H bf16 ----------------

__global__ LB void head_softmax(const bf16* __restrict__ H, const float* __restrict__ Wo2,
                                const float* __restrict__ bo2, float* __restrict__ out, int Nn){
  int gtid = blockIdx.x * 256 + threadIdx.x;
  int node = gtid >> 5;          // 32 lanes per node
  int lane = gtid & 31;
  if (node >= Nn) return;
  float l0 = 0.f, l1 = 0.f;
  #pragma unroll
  for (int kk = 0; kk < 4; ++kk){
    int k = lane + kk * 32;
    float h = (float)H[(size_t)node * 128 + k];
    l0 = fmaf(h, Wo2[k * 2 + 0], l0);
    l1 = fmaf(h, Wo2[k * 2 + 1], l1);
  }
  #pragma unroll
  for (int m = 16; m >= 1; m >>= 1){
    l0 += __shfl_xor(l0, m, 64);
    l1 += __shfl_xor(l1, m, 64);
  }
  if (lane == 0){
    l0 += bo2[0]; l1 += bo2[1];
    float mx = fmaxf(l0, l1);
    float e0 = __expf(l0 - mx), e1 = __expf(l1 - mx);
    float inv = 1.f / (e0 + e1);
    out[(size_t)node * 2 + 0] = e0 * inv;
    out[(size_t)node * 2 + 1] = e1 * inv;
  }
}

// ---------------- launch ----------------

extern "C" void kernel_launch(void* const* d_in, const int* in_sizes, int n_in,
                              void* d_out, int out_size, void* d_ws, size_t ws_size,
                              hipStream_t stream) {
  const float* des    = (const float*)d_in[0];
  const float* tweet  = (const float*)d_in[1];
  const float* prop   = (const float*)d_in[2];
  const int*   ei     = (const int*)d_in[3];
  const int*   et     = (const int*)d_in[4];
  const float* W_des  = (const float*)d_in[5];
  const float* b_des  = (const float*)d_in[6];
  const float* W_tw   = (const float*)d_in[7];
  const float* b_tw   = (const float*)d_in[8];
  const float* W_pr   = (const float*)d_in[9];
  const float* b_pr   = (const float*)d_in[10];
  const float* W_in   = (const float*)d_in[11];
  const float* b_in   = (const float*)d_in[12];
  const float* W_rel  = (const float*)d_in[13];
  const float* W_root = (const float*)d_in[14];
  const float* b_rg   = (const float*)d_in[15];
  const float* W_o1   = (const float*)d_in[16];
  const float* b_o1   = (const float*)d_in[17];
  const float* W_o2   = (const float*)d_in[18];
  const float* b_o2   = (const float*)d_in[19];

  const int Nn = in_sizes[0] / 768;         // 100000
  const int E  = in_sizes[4];               // 3200000
  const int q  = in_sizes[6];               // 32
  const int D  = in_sizes[12];              // 128
  const int R  = in_sizes[13] / (D * D);    // 2
  const int NS = Nn * R;
  const int K3 = 3 * q;                     // 96
  const int NB = cdiv(Nn, 512);             // 196 buckets

  // workspace carve (256B aligned)
  char* p = (char*)d_ws;
  auto carve = [&](size_t bytes) -> void* {
    void* r = (void*)p;
    p += (bytes + 255) & ~(size_t)255;
    return r;
  };
  int*   off     = (int*)  carve((size_t)(NS + 1) * 4);
  float* degInv  = (float*)carve((size_t)NS * 4);
  int*   srcS    = (int*)  carve((size_t)E * 4);
  int*   gCnt    = (int*)  carve(PNB * 4);
  int*   gCur    = (int*)  carve(PNB * 4);
  int*   bktBase = (int*)  carve((PNB + 1) * 4);
  int*   partSrc = (int*)  carve((size_t)E * 4);
  int*   partSeg = (int*)  carve((size_t)E * 4);
  bf16*  bufA    = (bf16*) carve((size_t)Nn * D * 2);
  bf16*  bufB    = (bf16*) carve((size_t)Nn * D * 2);
  bf16*  mean    = (bf16*) carve((size_t)Nn * R * D * 2);
  bf16*  dtp     = mean;                    // N x 96 bf16 overlays mean (dead before agg)
  bf16*  BT_des  = (bf16*) carve((size_t)q * 768 * 2);
  bf16*  BT_tw   = (bf16*) carve((size_t)q * 768 * 2);
  bf16*  BT_pr   = (bf16*) carve((size_t)q * 32 * 2);
  bf16*  BT_in   = (bf16*) carve((size_t)D * K3 * 2);
  bf16*  BT_st   = (bf16*) carve((size_t)D * 3 * D * 2);
  bf16*  BT_o1   = (bf16*) carve((size_t)D * D * 2);

  // ---- bucketed CSR build (once; shared by both RGCN layers) ----
  zero_int<<<1, 256, 0, stream>>>(gCnt, PNB);
  bucket_count_k<<<cdiv(E, CHUNK), 256, 0, stream>>>(ei, gCnt, E);
  bucket_scan_k<<<1, 256, 0, stream>>>(gCnt, bktBase, gCur, off, NB, E, NS);
  partition_k<<<cdiv(E, CHUNK), 256, 0, stream>>>(ei, et, gCur, partSrc, partSeg, E, R);
  bucket_csr_k<<<NB, 256, 0, stream>>>(partSrc, partSeg, bktBase, off, degInv, srcS, NS, R);

  // ---- weight prep (bf16, transposed, K zero-padded to mult of 32) ----
  prep_bt<<<cdiv(q * 768, 256), 256, 0, stream>>>(W_des, BT_des, 768, q, 768);
  prep_bt<<<cdiv(q * 768, 256), 256, 0, stream>>>(W_tw,  BT_tw,  768, q, 768);
  prep_bt<<<cdiv(q * 32, 256), 256, 0, stream>>>(W_pr,  BT_pr,  14,  q, 32);
  prep_bt<<<cdiv(D * K3, 256), 256, 0, stream>>>(W_in,  BT_in,  K3,  D, K3);
  prep_stack<<<cdiv(D * 3 * D, 256), 256, 0, stream>>>(W_root, W_rel, BT_st, D);
  prep_bt<<<cdiv(D * D, 256), 256, 0, stream>>>(W_o1,  BT_o1,  D,   D, D);

  const int gx = cdiv(Nn, 64);

  // ---- encoders -> dtp[:, 0:32 | 32:64 | 64:96] (fp32 A, bf16 C) ----
  gemm_mfma<32, true, false, false, true><<<dim3(gx, 1), 256, 0, stream>>>(
      des, 768, nullptr, 0, 0, BT_des, 768, dtp + 0, K3, b_des, Nn, 768);
  gemm_mfma<32, true, false, false, true><<<dim3(gx, 1), 256, 0, stream>>>(
      tweet, 768, nullptr, 0, 0, BT_tw, 768, dtp + q, K3, b_tw, Nn, 768);
  gemm_mfma<32, true, false, false, true><<<dim3(gx, 1), 256, 0, stream>>>(
      prop, 14, nullptr, 0, 0, BT_pr, 32, dtp + 2 * q, K3, b_pr, Nn, 14);

  // ---- x = lrelu(dtp @ W_in + b_in) -> bufA (bf16 A, bf16 C) ----
  gemm_mfma<64, true, false, true, true><<<dim3(gx, 2), 256, 0, stream>>>(
      dtp, K3, nullptr, 0, 0, BT_in, K3, bufA, D, b_in, Nn, K3);

  const int aggGrid = cdiv(NS * 64, 256);

  // ---- RGCN layer 1: bufA -> bufB (fused root+rel, K=384) ----
  agg_mean_k<<<aggGrid, 256, 0, stream>>>(bufA, srcS, off, degInv, mean, NS);
  gemm_mfma<64, false, true, true, true><<<dim3(gx, 2), 256, 0, stream>>>(
      bufA, D, mean, R * D, D, BT_st, 3 * D, bufB, D, b_rg, Nn, 3 * D);

  // ---- RGCN layer 2: bufB -> bufA ----
  agg_mean_k<<<aggGrid, 256, 0, stream>>>(bufB, srcS, off, degInv, mean, NS);
  gemm_mfma<64, false, true, true, true><<<dim3(gx, 2), 256, 0, stream>>>(
      bufB, D, mean, R * D, D, BT_st, 3 * D, bufA, D, b_rg, Nn, 3 * D);

  // ---- head ----
  gemm_mfma<64, true, false, true, true><<<dim3(gx, 2), 256, 0, stream>>>(
      bufA, D, nullptr, 0, 0, BT_o1, D, bufB, D, b_o1, Nn, D);
  head_softmax<<<cdiv(Nn * 32, 256), 256, 0, stream>>>(bufB, W_o2, b_o2, (float*)d_out, Nn);
}